// Round 8
// baseline (938.160 us; speedup 1.0000x reference)
//
#include <hip/hip_runtime.h>
#include <hip/hip_bf16.h>
#include <math.h>

#define N_ROWS 16384
#define DIM    256
#define NE     8192
#define QMARGIN 21   // ceil(eps/step)+1, step=2^-17, eps~1.5e-4

// ---- out layout (float indices) ----
// loss @0 | z_q_st @1 (4194304) | perp @4194305 | one_hot @4194306 (134217728)
// indices @138412034 (16384)
//
// ---- scratch INSIDE one_hot region (d_ws untouched), 16B-aligned ----
// SOFF = 4194308
// zf    @ SOFF+0         (4194304 f32)   z as (N,D)
// zfb   @ SOFF+4194304   (4194304 bf16)  fragment-order bf16 z
// ewb   @ SOFF+6291456   (2097152 bf16)  fragment-order bf16 codebook
// part  @ SOFF+7340032   (524288 i32)    per row: 8 byc x 2 wn x (k1,k2)
// lprt  @ SOFF+7864320   (16384 f32)
// ghist @ SOFF+7880704   (8192 i32)      zeroed via hipMemsetAsync each call
// ends @ out[12083204] << 138412034; k_onehot overwrites last.
#define SOFF 4194308

typedef __bf16 bf16x8 __attribute__((ext_vector_type(8)));
typedef float  f32x4  __attribute__((ext_vector_type(4)));
typedef float  vf4    __attribute__((ext_vector_type(4)));

__device__ __forceinline__ void gload_lds16(const __bf16* g, __bf16* l) {
  __builtin_amdgcn_global_load_lds(
      (const __attribute__((address_space(1))) unsigned int*)g,
      (__attribute__((address_space(3))) unsigned int*)l, 16, 0, 0);
}

// ---------- kernel 1: transpose z -> zf (N,D) fp32 AND zfb fragment bf16 ----------
__global__ void k_prep(const float* __restrict__ z, float* __restrict__ zf,
                       __bf16* __restrict__ zfb) {
  __shared__ float tile[32][33];
  int ct = blockIdx.x, ht = blockIdx.y, b = blockIdx.z;
  int tx = threadIdx.x & 31, ty = threadIdx.x >> 5;
  int c0 = ct * 32, hw0 = ht * 32;
  const size_t zb = (size_t)b * 256 * 1024;
#pragma unroll
  for (int p = 0; p < 4; ++p) {
    int c = p * 8 + ty;
    tile[c][tx] = z[zb + (size_t)(c0 + c) * 1024 + hw0 + tx];
  }
  __syncthreads();
#pragma unroll
  for (int p = 0; p < 4; ++p) {
    int r = p * 8 + ty;
    zf[(size_t)(b * 1024 + hw0 + r) * DIM + c0 + tx] = tile[tx][r];
  }
  if (threadIdx.x < 128) {
    int r = threadIdx.x >> 2, kc = threadIdx.x & 3;
    int row = b * 1024 + hw0 + r;
    bf16x8 v;
#pragma unroll
    for (int j = 0; j < 8; ++j) v[j] = (__bf16)tile[kc * 8 + j][r];
    int tn = row >> 7, g = (row >> 4) & 7, m15 = row & 15, kt = c0 >> 5;
    *(bf16x8*)(zfb + (size_t)tn * 32768 + kt * 4096 + g * 512 + (kc * 16 + m15) * 8) = v;
  }
}

// ---------- kernel 2: codebook fp32 -> bf16 fragment order ----------
__global__ void k_cvt_e(const float* __restrict__ ew, __bf16* __restrict__ ewb) {
  int gid = blockIdx.x * 256 + threadIdx.x;  // 0..262143
  int r = gid >> 5, kc8 = gid & 31;
  const float* s = ew + (size_t)r * DIM + kc8 * 8;
  float4 v0 = *(const float4*)s, v1 = *(const float4*)(s + 4);
  bf16x8 v = {(__bf16)v0.x, (__bf16)v0.y, (__bf16)v0.z, (__bf16)v0.w,
              (__bf16)v1.x, (__bf16)v1.y, (__bf16)v1.z, (__bf16)v1.w};
  int t = r >> 7, g = (r >> 4) & 7, m15 = r & 15, kt = kc8 >> 2, kc = kc8 & 3;
  *(bf16x8*)(ewb + (size_t)t * 32768 + kt * 4096 + g * 512 + (kc * 16 + m15) * 8) = v;
}

// ---------- kernel 3: barrier-free MFMA scores ----------
// A persistent in LDS (staged once); B global->VGPR, 2-deep register prefetch;
// running per-lane top-2 packed keys; single 16-lane merge at the end.
__global__ __launch_bounds__(256, 2) void k_score(const __bf16* __restrict__ zfb,
                                                  const __bf16* __restrict__ ewb,
                                                  int2* __restrict__ part2) {
  __shared__ __align__(16) __bf16 Afull[32768];   // 64 KB: full 128x256 A tile
  const int tid = threadIdx.x;
  const int lane = tid & 63, wave = tid >> 6;
  const int wm = wave >> 1, wn = wave & 1;
  const int quad = lane >> 4, l15 = lane & 15;
  const int bx = blockIdx.x, byc = blockIdx.y;
  const __bf16* Ag = zfb + (size_t)bx * 32768;
  const __bf16* Bg = ewb + (size_t)byc * 262144 + wn * 2048 + lane * 8;

  // stage A once (16 KB per wave)
  {
    const int base = wave * 8192;
#pragma unroll
    for (int i = 0; i < 16; ++i)
      gload_lds16(Ag + base + i * 512 + lane * 8, Afull + base + i * 512);
  }
  // register prefetch of B for iters 0,1
  bf16x8 pf[2][4];
#pragma unroll
  for (int ni = 0; ni < 4; ++ni) pf[0][ni] = *(const bf16x8*)(Bg + ni * 512);
#pragma unroll
  for (int ni = 0; ni < 4; ++ni) pf[1][ni] = *(const bf16x8*)(Bg + 4096 + ni * 512);

  f32x4 acc[4][4];
#pragma unroll
  for (int i = 0; i < 4; ++i)
#pragma unroll
    for (int j = 0; j < 4; ++j) acc[i][j] = (f32x4){0.f, 0.f, 0.f, 0.f};
  int r1[16], r2[16];
#pragma unroll
  for (int i = 0; i < 16; ++i) { r1[i] = 0x7fffffff; r2[i] = 0x7fffffff; }

  __syncthreads();  // the ONLY barrier: A tile ready

  for (int bt = 0; bt < 8; ++bt) {
#pragma unroll
    for (int kt = 0; kt < 8; ++kt) {
      const int it = bt * 8 + kt;
      const int b = it & 1;
      bf16x8 af[4];
#pragma unroll
      for (int mi = 0; mi < 4; ++mi)
        af[mi] = *(const bf16x8*)(Afull + kt * 4096 + (wm * 4 + mi) * 512 + lane * 8);
#pragma unroll
      for (int mi = 0; mi < 4; ++mi)
#pragma unroll
        for (int ni = 0; ni < 4; ++ni)
          acc[mi][ni] = __builtin_amdgcn_mfma_f32_16x16x32_bf16(af[mi], pf[b][ni],
                                                                acc[mi][ni], 0, 0, 0);
      if (it < 62) {
        const int nx = it + 2;
        const __bf16* src = Bg + (nx >> 3) * 32768 + (nx & 7) * 4096;
#pragma unroll
        for (int ni = 0; ni < 4; ++ni) pf[b][ni] = *(const bf16x8*)(src + ni * 512);
      }
    }
    // epilogue: quantize (single-rounding fma, no clamp) + running top-2
    const int colb = byc * 1024 + bt * 128 + wn * 64;
#pragma unroll
    for (int mi = 0; mi < 4; ++mi) {
#pragma unroll
      for (int rg = 0; rg < 4; ++rg) {
        const int idx = mi * 4 + rg;
        int q0 = (int)__builtin_fmaf(acc[mi][0][rg], -262144.f, 131072.f);
        int q1 = (int)__builtin_fmaf(acc[mi][1][rg], -262144.f, 131072.f);
        int q2 = (int)__builtin_fmaf(acc[mi][2][rg], -262144.f, 131072.f);
        int q3 = (int)__builtin_fmaf(acc[mi][3][rg], -262144.f, 131072.f);
        int k0 = (q0 << 13) | (colb + l15);
        int k1 = (q1 << 13) | (colb + 16 + l15);
        int k2 = (q2 << 13) | (colb + 32 + l15);
        int k3 = (q3 << 13) | (colb + 48 + l15);
        int a = min(k0, k1), bb = max(k0, k1);
        int c = min(k2, k3), dd = max(k2, k3);
        int t1 = min(a, c);
        int t2 = min(max(a, c), min(bb, dd));
        int n1 = min(r1[idx], t1);
        int n2 = min(max(r1[idx], t1), min(r2[idx], t2));
        r1[idx] = n1; r2[idx] = n2;
      }
    }
#pragma unroll
    for (int i = 0; i < 4; ++i)
#pragma unroll
      for (int j = 0; j < 4; ++j) acc[i][j] = (f32x4){0.f, 0.f, 0.f, 0.f};
  }

  // single final 16-lane lex merge + store
#pragma unroll
  for (int mi = 0; mi < 4; ++mi) {
#pragma unroll
    for (int rg = 0; rg < 4; ++rg) {
      const int idx = mi * 4 + rg;
      int k1 = r1[idx], k2 = r2[idx];
#pragma unroll
      for (int d = 1; d < 16; d <<= 1) {
        int o1 = __shfl_xor(k1, d), o2 = __shfl_xor(k2, d);
        k2 = min(max(k1, o1), min(k2, o2));
        k1 = min(k1, o1);
      }
      if (l15 == 0) {
        int row = bx * 128 + wm * 64 + mi * 16 + quad * 4 + rg;
        int2 v; v.x = k1; v.y = k2;
        part2[row * 16 + byc * 2 + wn] = v;
      }
    }
  }
}

// ---------- numpy-pairwise-exact sum of squares over 128 ----------
__device__ __forceinline__ float np_sumsq_128(const float* __restrict__ p) {
  float r[8];
#pragma unroll
  for (int j = 0; j < 8; ++j) r[j] = __fmul_rn(p[j], p[j]);
  for (int i = 8; i < 128; i += 8) {
#pragma unroll
    for (int j = 0; j < 8; ++j) r[j] = __fadd_rn(r[j], __fmul_rn(p[i + j], p[i + j]));
  }
  return __fadd_rn(__fadd_rn(__fadd_rn(r[0], r[1]), __fadd_rn(r[2], r[3])),
                   __fadd_rn(__fadd_rn(r[4], r[5]), __fadd_rn(r[6], r[7])));
}

// ---------- kernel 4: wave-per-row candidate filter + exact fp32 rescore ----------
__global__ __launch_bounds__(256) void k_pick(const int2* __restrict__ part2,
                                              const float* __restrict__ zf,
                                              const float* __restrict__ ew,
                                              float* __restrict__ idxF,
                                              float* __restrict__ losspart,
                                              int* __restrict__ ghist) {
  __shared__ int cand[4][40];
  __shared__ int cnts[4];
  const int t = threadIdx.x, lane = t & 63, wv = t >> 6;
  const int row = blockIdx.x * 4 + wv;
  if (lane == 0) cnts[wv] = 0;
  int2 pv;
  if (lane < 16) pv = part2[row * 16 + lane];
  else { pv.x = 0x7fffffff; pv.y = 0x7fffffff; }
  int kmin = pv.x;
#pragma unroll
  for (int d = 1; d < 64; d <<= 1) kmin = min(kmin, __shfl_xor(kmin, d));
  const int qthr = min((kmin >> 13) + QMARGIN, 262143);
  const int kthr = (qthr << 13) | 8191;
  __syncthreads();
  if (lane < 16) {
    if (pv.x <= kthr) { int p = atomicAdd(&cnts[wv], 1); cand[wv][p] = pv.x & 8191; }
    if (pv.y <= kthr) { int p = atomicAdd(&cnts[wv], 1); cand[wv][p] = pv.y & 8191; }
  }
  __syncthreads();
  const int cnt = cnts[wv];
  const float* zr = zf + (size_t)row * DIM;
  float bd = INFINITY; int bj = 0x7fffffff;
  if (lane < cnt) {
    int j = cand[wv][lane];
    const float* e = ew + (size_t)j * DIM;
    float acc = 0.f;
    for (int k = 0; k < DIM; ++k) acc = __builtin_fmaf(zr[k], e[k], acc);  // round-3 order
    float esq = __fadd_rn(np_sumsq_128(e), np_sumsq_128(e + 128));
    float zsq = __fadd_rn(np_sumsq_128(zr), np_sumsq_128(zr + 128));
    bd = __fsub_rn(__fadd_rn(zsq, esq), __fmul_rn(2.0f, acc));
    bj = j;
  }
#pragma unroll
  for (int d = 1; d < 64; d <<= 1) {
    float od = __shfl_xor(bd, d); int oj = __shfl_xor(bj, d);
    if (od < bd || (od == bd && oj < bj)) { bd = od; bj = oj; }
  }
  // loss partial (round-3 k_merge numerics)
  int c = lane * 4;
  float4 e4 = *reinterpret_cast<const float4*>(ew + (size_t)bj * DIM + c);
  float4 z4 = *reinterpret_cast<const float4*>(zr + c);
  float t0 = __fsub_rn(e4.x, z4.x), t1 = __fsub_rn(e4.y, z4.y);
  float t2 = __fsub_rn(e4.z, z4.z), t3 = __fsub_rn(e4.w, z4.w);
  float s = __fadd_rn(__fadd_rn(__fmul_rn(t0, t0), __fmul_rn(t1, t1)),
                      __fadd_rn(__fmul_rn(t2, t2), __fmul_rn(t3, t3)));
#pragma unroll
  for (int d = 1; d < 64; d <<= 1) s += __shfl_xor(s, d);
  if (lane == 0) {
    idxF[row] = (float)bj;
    losspart[row] = s;
    atomicAdd(&ghist[bj], 1);
  }
}

// ---------- kernel 5: loss + perplexity (hist precomputed) ----------
__global__ __launch_bounds__(256) void k_scalars(const int* __restrict__ ghist,
                                                 const float* __restrict__ losspart,
                                                 float* __restrict__ out) {
  __shared__ float red[256];
  int t = threadIdx.x;
  float es = 0.f;
  for (int i = t; i < NE; i += 256) {
    float p = (float)ghist[i] * (1.0f / 16384.0f);
    es += p * logf(p + 1e-10f);
  }
  float ls = 0.f;
  for (int i = t; i < N_ROWS; i += 256) ls += losspart[i];
  red[t] = es; __syncthreads();
  for (int w = 128; w > 0; w >>= 1) { if (t < w) red[t] += red[t + w]; __syncthreads(); }
  float esum = red[0]; __syncthreads();
  red[t] = ls; __syncthreads();
  for (int w = 128; w > 0; w >>= 1) { if (t < w) red[t] += red[t + w]; __syncthreads(); }
  if (t == 0) {
    out[4194305] = expf(-esum);
    float m = red[0] * (1.0f / 4194304.0f);
    out[0] = __fadd_rn(m, __fmul_rn(0.25f, m));
  }
}

// ---------- kernel 6: z_q_st back to (B,C,H,W) ----------
__global__ void k_zq_out(const float* __restrict__ z, const float* __restrict__ ew,
                         const float* __restrict__ idxF, float* __restrict__ out) {
  __shared__ float tileE[32][33];
  __shared__ int sidx[32];
  int ct = blockIdx.x, ht = blockIdx.y, b = blockIdx.z;
  int tx = threadIdx.x & 31, ty = threadIdx.x >> 5;
  int c0 = ct * 32, hw0 = ht * 32;
  if (threadIdx.x < 32) sidx[threadIdx.x] = (int)idxF[b * 1024 + hw0 + threadIdx.x];
  __syncthreads();
#pragma unroll
  for (int p = 0; p < 4; ++p) {
    int r = p * 8 + ty;
    tileE[tx][r] = ew[(size_t)sidx[r] * DIM + c0 + tx];
  }
  __syncthreads();
  float* outq = out + 1;
#pragma unroll
  for (int p = 0; p < 4; ++p) {
    int cl = p * 8 + ty;
    size_t gi = (size_t)(b * 256 + c0 + cl) * 1024 + hw0 + tx;
    float zv = z[gi];
    outq[gi] = __fadd_rn(zv, __fsub_rn(tileE[cl][tx], zv));
  }
}

// ---------- kernel 7 (LAST): one_hot, ext-vector NT stores ----------
__global__ void k_onehot(const float* __restrict__ idxF, float* __restrict__ out) {
  int row = blockIdx.x;
  int t = threadIdx.x;
  int idx = (int)idxF[row];
  float* p = out + 4194306 + (size_t)row * NE;
  if (t == 0) {
    float2 h; h.x = (0 == idx) ? 1.f : 0.f; h.y = (1 == idx) ? 1.f : 0.f;
    *(float2*)p = h;
    float2 q; q.x = (8190 == idx) ? 1.f : 0.f; q.y = (8191 == idx) ? 1.f : 0.f;
    *(float2*)(p + 8190) = q;
  }
  vf4* b4 = (vf4*)(p + 2);
#pragma unroll
  for (int it = 0; it < 8; ++it) {
    int i = it * 256 + t;
    if (i < 2047) {
      int c = 2 + i * 4;
      vf4 v;
      v.x = (c     == idx) ? 1.f : 0.f;
      v.y = (c + 1 == idx) ? 1.f : 0.f;
      v.z = (c + 2 == idx) ? 1.f : 0.f;
      v.w = (c + 3 == idx) ? 1.f : 0.f;
      __builtin_nontemporal_store(v, b4 + i);
    }
  }
}

extern "C" void kernel_launch(void* const* d_in, const int* in_sizes, int n_in,
                              void* d_out, int out_size, void* d_ws, size_t ws_size,
                              hipStream_t stream) {
  const float* z  = (const float*)d_in[0];
  const float* ew = (const float*)d_in[1];
  float* out = (float*)d_out;
  float*  zf    = out + SOFF;
  __bf16* zfb   = (__bf16*)(out + SOFF + 4194304);
  __bf16* ewb   = (__bf16*)(out + SOFF + 6291456);
  int2*   part2 = (int2*)(out + SOFF + 7340032);
  float*  lprt  = out + SOFF + 7864320;
  int*    ghist = (int*)(out + SOFF + 7880704);
  float*  idxF  = out + 138412034;

  hipMemsetAsync(ghist, 0, NE * sizeof(int), stream);
  k_prep<<<dim3(8, 32, 16), 256, 0, stream>>>(z, zf, zfb);
  k_cvt_e<<<dim3(1024), 256, 0, stream>>>(ew, ewb);
  k_score<<<dim3(128, 8), 256, 0, stream>>>(zfb, ewb, part2);
  k_pick<<<dim3(4096), 256, 0, stream>>>(part2, zf, ew, idxF, lprt, ghist);
  k_scalars<<<1, 256, 0, stream>>>(ghist, lprt, out);
  k_zq_out<<<dim3(8, 32, 16), 256, 0, stream>>>(z, ew, idxF, out);
  k_onehot<<<dim3(16384), 256, 0, stream>>>(idxF, out);
}